// Round 2
// baseline (782.749 us; speedup 1.0000x reference)
//
#include <hip/hip_runtime.h>
#include <hip/hip_cooperative_groups.h>

namespace cg = cooperative_groups;

typedef __bf16 bf16_t;
typedef __bf16 bf16x8 __attribute__((ext_vector_type(8)));
typedef float f32x4 __attribute__((ext_vector_type(4)));
typedef unsigned short us4 __attribute__((ext_vector_type(4)));
typedef unsigned short us8 __attribute__((ext_vector_type(8)));

#define LO4(v) __builtin_shufflevector(v, v, 0, 1, 2, 3)
#define HI4(v) __builtin_shufflevector(v, v, 4, 5, 6, 7)

// ---------------- foveation unit ----------------
template<int F>
__device__ __forceinline__ void fov_scale(const float* __restrict__ xb,
                                          bf16_t* __restrict__ gb,
                                          int r0, int c0, int base, int count, int kidx)
{
  constexpr float inv = 1.0f / (F * F);
  for (int i = threadIdx.x; i < count; i += 256) {
    const int idx = base + i;              // 0..3071 within this scale (c*1024 + gy*32 + gx)
    const int ch  = idx >> 10;
    const int rem = idx & 1023;
    const int gy  = rem >> 5, gx = rem & 31;
    const float* xc = xb + ch * 50176;
    float sum = 0.0f;
    const int rbase = r0 + gy * F, cbase = c0 + gx * F;
#pragma unroll
    for (int dy = 0; dy < F; ++dy) {
      const int rr = rbase + dy;
      if ((unsigned)rr < 224u) {
#pragma unroll
        for (int dx = 0; dx < F; ++dx) {
          const int cc = cbase + dx;
          if ((unsigned)cc < 224u) sum += xc[rr * 224 + cc];
        }
      }
    }
    gb[kidx * 3072 + idx] = (bf16_t)(sum * inv);
  }
}

__device__ __forceinline__ void fov_unit(const float* __restrict__ x,
                                         const float* __restrict__ l,
                                         bf16_t* __restrict__ g, int u)
{
  const int b = u & 255;
  const int y = u >> 8;       // 7 work partitions weighted by read cost
  const float l0 = l[2 * b], l1 = l[2 * b + 1];
  // match reference exactly: (int)(0.5f * ((l + 1.0f) * 224.0f)), trunc (values >= 0)
  const int st0 = (int)(0.5f * ((l0 + 1.0f) * 224.0f));  // col start
  const int st1 = (int)(0.5f * ((l1 + 1.0f) * 224.0f));  // row start
  const float* xb = x + (size_t)b * 3 * 50176;
  bf16_t* gb = g + (size_t)b * 9216;
  if (y == 0) {
    fov_scale<1>(xb, gb, st1 - 17, st0 - 17, 0, 3072, 0);              // pad = 32/2+1
  } else if (y <= 2) {
    fov_scale<2>(xb, gb, st1 - 33, st0 - 33, (y - 1) * 1536, 1536, 1); // pad = 64/2+1
  } else {
    fov_scale<4>(xb, gb, st1 - 65, st0 - 65, (y - 3) * 768, 768, 2);   // pad = 128/2+1
  }
}

// ---------------- 64x64 fp32 -> bf16 transpose tile ----------------
// src: tile origin of [64 k][64 n] fp32, row stride srcld.
// dst: tile origin of [64 n][64 k] bf16 (as ushort), row stride dstld.
// T: >= 64*72 ushorts of LDS. Barrier at entry protects the caller's previous LDS use.
__device__ __forceinline__ void transpose_tile(const float* __restrict__ src, int srcld,
                                               unsigned short* __restrict__ dst, int dstld,
                                               unsigned short* __restrict__ T)
{
  const int t = threadIdx.x;
  __syncthreads();
#pragma unroll
  for (int it = 0; it < 16; ++it) {
    const int idx = it * 256 + t;        // 0..4095
    const int kk = idx >> 6, nn = idx & 63;   // coalesced along nn
    T[nn * 72 + kk] = __builtin_bit_cast(unsigned short, (bf16_t)src[(size_t)kk * srcld + nn]);
  }
  __syncthreads();
#pragma unroll
  for (int it = 0; it < 2; ++it) {
    const int q = it * 256 + t;          // 0..511
    const int n = q >> 3, kc = (q & 7) * 8;
    *(us8*)(dst + (size_t)n * dstld + kc) = *(const us8*)&T[n * 72 + kc];
  }
}

// ---------------- split-K bf16 MFMA GEMM body (both operands k-contiguous bf16) ----------------
// A: bf16 [256 x KFULL] row-major. Bt: bf16 [N x KFULL] row-major (pre-transposed weights).
// Writes fp32 partials: part[bz][m][n]. sh: >= (BM+BN)*36 ushorts of LDS.
template<int BM, int BN, int KCHUNK, int NDIM, int KFULL>
__device__ __forceinline__ void gemm_body(const bf16_t* __restrict__ A,
                                          const bf16_t* __restrict__ Bt,
                                          float* __restrict__ part,
                                          int bx, int by, int bz,
                                          unsigned short* __restrict__ sh)
{
  constexpr int WROWS = BM / 4;     // rows per wave
  constexpr int SM = WROWS / 16;    // 16-row subtiles per wave
  constexpr int SN = BN / 16;       // 16-col subtiles
  constexpr int LDA = 36;           // LDS row stride (ushorts): conflict-benign for b64 frag reads
  constexpr int NLA = BM / 64;      // us8 A loads per thread per k-step
  unsigned short* Al = sh;
  unsigned short* Bl = sh + BM * LDA;
  const int t = threadIdx.x;
  const int w = t >> 6, lane = t & 63;
  const int lr = lane & 15, kg = lane >> 4;
  const int bm0 = bx * BM, bn0 = by * BN;
  const int ks0 = bz * KCHUNK;
  const unsigned short* Au = (const unsigned short*)A;
  const unsigned short* Bu = (const unsigned short*)Bt;

  const int bn = t >> 2, bkb = (t & 3) * 8;
  const bool bld = (t < BN * 4);    // wave-uniform (multiple-of-64 cut)

  f32x4 acc[SM][SN] = {};
  us8 pa[NLA], pb;

  // prologue: load k-tile 0 into regs
#pragma unroll
  for (int i = 0; i < NLA; ++i) {
    const int q = t + 256 * i;
    pa[i] = *(const us8*)(Au + (size_t)(bm0 + (q >> 2)) * KFULL + ks0 + (q & 3) * 8);
  }
  if (bld) pb = *(const us8*)(Bu + (size_t)(bn0 + bn) * KFULL + ks0 + bkb);

  for (int k0 = 0; k0 < KCHUNK; k0 += 32) {
    // ---- regs -> LDS ----
#pragma unroll
    for (int i = 0; i < NLA; ++i) {
      const int q = t + 256 * i;
      const int m = q >> 2, kb = (q & 3) * 8;
      *(us4*)(&Al[m * LDA + kb])     = LO4(pa[i]);
      *(us4*)(&Al[m * LDA + kb + 4]) = HI4(pa[i]);
    }
    if (bld) {
      *(us4*)(&Bl[bn * LDA + bkb])     = LO4(pb);
      *(us4*)(&Bl[bn * LDA + bkb + 4]) = HI4(pb);
    }
    __syncthreads();
    // ---- prefetch next k-tile into regs (overlaps with frag reads + MFMA) ----
    if (k0 + 32 < KCHUNK) {
      const int knext = ks0 + k0 + 32;
#pragma unroll
      for (int i = 0; i < NLA; ++i) {
        const int q = t + 256 * i;
        pa[i] = *(const us8*)(Au + (size_t)(bm0 + (q >> 2)) * KFULL + knext + (q & 3) * 8);
      }
      if (bld) pb = *(const us8*)(Bu + (size_t)(bn0 + bn) * KFULL + knext + bkb);
    }
    // ---- fragments (A[m=lr][k=kg*8+j], B[n=lr][k=kg*8+j]) + MFMA ----
    bf16x8 af[SM], bfr[SN];
#pragma unroll
    for (int sm = 0; sm < SM; ++sm) {
      const unsigned short* p = &Al[(w * WROWS + sm * 16 + lr) * LDA + kg * 8];
      us4 x0 = *(const us4*)p;
      us4 x1 = *(const us4*)(p + 4);
      af[sm] = __builtin_bit_cast(bf16x8, __builtin_shufflevector(x0, x1, 0, 1, 2, 3, 4, 5, 6, 7));
    }
#pragma unroll
    for (int sn = 0; sn < SN; ++sn) {
      const unsigned short* p = &Bl[(sn * 16 + lr) * LDA + kg * 8];
      us4 x0 = *(const us4*)p;
      us4 x1 = *(const us4*)(p + 4);
      bfr[sn] = __builtin_bit_cast(bf16x8, __builtin_shufflevector(x0, x1, 0, 1, 2, 3, 4, 5, 6, 7));
    }
#pragma unroll
    for (int sm = 0; sm < SM; ++sm)
#pragma unroll
      for (int sn = 0; sn < SN; ++sn)
        acc[sm][sn] = __builtin_amdgcn_mfma_f32_16x16x32_bf16(af[sm], bfr[sn], acc[sm][sn], 0, 0, 0);
    __syncthreads();
  }
  // ---- write fp32 partials (C/D layout: col=lr, row=kg*4+r) ----
  float* outp = part + (size_t)bz * ((size_t)256 * NDIM);
#pragma unroll
  for (int sm = 0; sm < SM; ++sm)
#pragma unroll
    for (int sn = 0; sn < SN; ++sn)
#pragma unroll
      for (int r = 0; r < 4; ++r) {
        const int gm = bm0 + w * WROWS + sm * 16 + kg * 4 + r;
        const int gn = bn0 + sn * 16 + lr;
        outp[(size_t)gm * NDIM + gn] = acc[sm][sn][r];
      }
}

// ---------------- persistent cooperative mega-kernel: all 5 phases, 4 grid syncs ----------------
__global__ __launch_bounds__(256, 2) void mega(const float* __restrict__ x,
                                               const float* __restrict__ lprev,
                                               const float* __restrict__ W1,
                                               const float* __restrict__ b1,
                                               const float* __restrict__ W2,
                                               const float* __restrict__ b2,
                                               const float* __restrict__ W3,
                                               const float* __restrict__ b3,
                                               const float* __restrict__ W4,
                                               const float* __restrict__ b4,
                                               bf16_t* __restrict__ glimpse,
                                               bf16_t* __restrict__ A2,
                                               float* __restrict__ part1,
                                               float* __restrict__ part2,
                                               bf16_t* __restrict__ W1t,
                                               bf16_t* __restrict__ W34t,
                                               float* __restrict__ out)
{
  __shared__ unsigned short sh[(128 + 64) * 36];   // 13824 B: gemm tiles / transpose buffer union
  const int t = threadIdx.x;
  cg::grid_group grid = cg::this_grid();

  // ---- phase A: foveation (units 0..1791) + weight transpose/convert (1792..5119) ----
  for (int u = blockIdx.x; u < 5120; u += 512) {
    if (u < 1792) {
      fov_unit(x, lprev, glimpse, u);
    } else if (u < 4096) {
      const int cid = u - 1792;          // 144 ktiles x 16 ntiles
      const int kt = cid >> 4, nt = cid & 15;
      transpose_tile(W1 + (size_t)(kt * 64) * 1024 + nt * 64, 1024,
                     (unsigned short*)W1t + (size_t)(nt * 64) * 9216 + kt * 64, 9216, sh);
    } else {
      const int cid = u - 4096;          // 32 ktiles x 32 ntiles
      const int kt = cid >> 5, nt = cid & 31;
      const int k0 = kt * 64;            // tile never straddles k=1024 (64 | 1024)
      const float* src = (k0 < 1024) ? (W3 + (size_t)k0 * 2048 + nt * 64)
                                     : (W4 + (size_t)(k0 - 1024) * 2048 + nt * 64);
      transpose_tile(src, 2048,
                     (unsigned short*)W34t + (size_t)(nt * 64) * 2048 + k0, 2048, sh);
    }
  }
  __threadfence();
  grid.sync();

  // ---- phase B: GEMM1  M=256,N=1024,K=9216; 128x64 tiles, splitK=16 -> 512 virtual blocks ----
  {
    const int u = blockIdx.x;
    gemm_body<128, 64, 576, 1024, 9216>(glimpse, W1t, part1, u & 1, (u >> 1) & 15, u >> 5, sh);
  }
  __threadfence();
  grid.sync();

  // ---- phase C: reduce part1 (16) + bias + relu -> bf16 A2; also l_out path ----
  for (int blk = blockIdx.x; blk < 2048; blk += 512) {
    const int idx = blk * 256 + t;       // 0..524287
    const int row = idx >> 11, col = idx & 2047;
    float s;
    if (col < 1024) {
      s = b1[col];
#pragma unroll
      for (int i = 0; i < 16; ++i) s += part1[i * 262144 + row * 1024 + col];
    } else {
      const int n = col - 1024;
      s = fmaf(lprev[2 * row], W2[n], fmaf(lprev[2 * row + 1], W2[1024 + n], b2[n]));
    }
    A2[idx] = (bf16_t)fmaxf(s, 0.0f);
  }
  __threadfence();
  grid.sync();

  // ---- phase D: GEMM2  M=256,N=2048,K=2048; 128x64 tiles, splitK=8 -> 512 virtual blocks ----
  {
    const int u = blockIdx.x;
    gemm_body<128, 64, 256, 2048, 2048>(A2, W34t, part2, u & 1, (u >> 1) & 31, u >> 6, sh);
  }
  __threadfence();
  grid.sync();

  // ---- phase E: reduce part2 (8) + (b3+b4) + relu -> fp32 out ----
  for (int blk = blockIdx.x; blk < 2048; blk += 512) {
    const int idx = blk * 256 + t;       // 0..524287
    const int col = idx & 2047;
    float s = b3[col] + b4[col];
#pragma unroll
    for (int i = 0; i < 8; ++i) s += part2[i * 524288 + idx];
    out[idx] = fmaxf(s, 0.0f);
  }
}

// ================= fallback path: round-1 5-kernel pipeline (proven @287us) =================
__global__ __launch_bounds__(256) void fov_conv_kernel(const float* __restrict__ x,
                                                       const float* __restrict__ l,
                                                       bf16_t* __restrict__ g,
                                                       const float* __restrict__ W1,
                                                       const float* __restrict__ W3,
                                                       const float* __restrict__ W4,
                                                       bf16_t* __restrict__ W1t,
                                                       bf16_t* __restrict__ W34t)
{
  __shared__ unsigned short T[64 * 72];
  const int bid = blockIdx.x;
  if (bid < 1792) {
    fov_unit(x, l, g, bid);
  } else if (bid < 4096) {
    const int cid = bid - 1792;
    const int kt = cid >> 4, nt = cid & 15;
    transpose_tile(W1 + (size_t)(kt * 64) * 1024 + nt * 64, 1024,
                   (unsigned short*)W1t + (size_t)(nt * 64) * 9216 + kt * 64, 9216, T);
  } else {
    const int cid = bid - 4096;
    const int kt = cid >> 5, nt = cid & 31;
    const int k0 = kt * 64;
    const float* src = (k0 < 1024) ? (W3 + (size_t)k0 * 2048 + nt * 64)
                                   : (W4 + (size_t)(k0 - 1024) * 2048 + nt * 64);
    transpose_tile(src, 2048,
                   (unsigned short*)W34t + (size_t)(nt * 64) * 2048 + k0, 2048, T);
  }
}

template<int BM, int BN, int KCHUNK, int NDIM, int KFULL>
__global__ __launch_bounds__(256) void gemm_bb(const bf16_t* __restrict__ A,
                                               const bf16_t* __restrict__ Bt,
                                               float* __restrict__ part)
{
  __shared__ unsigned short sh[(BM + BN) * 36];
  gemm_body<BM, BN, KCHUNK, NDIM, KFULL>(A, Bt, part, blockIdx.x, blockIdx.y, blockIdx.z, sh);
}

__global__ __launch_bounds__(256) void fuse_mid(const float* __restrict__ part1,
                                                const float* __restrict__ b1,
                                                const float* __restrict__ lprev,
                                                const float* __restrict__ W2,
                                                const float* __restrict__ b2,
                                                bf16_t* __restrict__ A2)
{
  const int idx = blockIdx.x * 256 + threadIdx.x;
  const int row = idx >> 11, col = idx & 2047;
  float s;
  if (col < 1024) {
    s = b1[col];
#pragma unroll
    for (int i = 0; i < 16; ++i) s += part1[i * 262144 + row * 1024 + col];
  } else {
    const int n = col - 1024;
    s = fmaf(lprev[2 * row], W2[n], fmaf(lprev[2 * row + 1], W2[1024 + n], b2[n]));
  }
  A2[idx] = (bf16_t)fmaxf(s, 0.0f);
}

__global__ __launch_bounds__(256) void epilogue2(const float* __restrict__ part2,
                                                 const float* __restrict__ b3,
                                                 const float* __restrict__ b4,
                                                 float* __restrict__ out)
{
  const int idx = blockIdx.x * 256 + threadIdx.x;
  const int col = idx & 2047;
  float s = b3[col] + b4[col];
#pragma unroll
  for (int i = 0; i < 8; ++i) s += part2[i * 524288 + idx];
  out[idx] = fmaxf(s, 0.0f);
}

extern "C" void kernel_launch(void* const* d_in, const int* in_sizes, int n_in,
                              void* d_out, int out_size, void* d_ws, size_t ws_size,
                              hipStream_t stream)
{
  const float* x     = (const float*)d_in[0];
  const float* lprev = (const float*)d_in[1];
  const float* W1    = (const float*)d_in[2];   // (9216, 1024)
  const float* b1    = (const float*)d_in[3];
  const float* W2    = (const float*)d_in[4];   // (2, 1024)
  const float* b2    = (const float*)d_in[5];
  const float* W3    = (const float*)d_in[6];   // (1024, 2048)
  const float* b3    = (const float*)d_in[7];
  const float* W4    = (const float*)d_in[8];   // (1024, 2048)
  const float* b4    = (const float*)d_in[9];
  float* out = (float*)d_out;

  // workspace layout (all 16B aligned), total ~66.6 MB
  char* ws = (char*)d_ws;
  bf16_t* glimpse = (bf16_t*)ws;                 // 256*9216*2    =  4,718,592 B
  bf16_t* A2      = (bf16_t*)(ws + 4718592);     // 256*2048*2    =  1,048,576 B
  float*  part1   = (float*)(ws + 5767168);      // 16*256*1024*4 = 16,777,216 B
  float*  part2   = (float*)(ws + 22544384);     // 8*256*2048*4  = 16,777,216 B
  bf16_t* W1t     = (bf16_t*)(ws + 39321600);    // 1024*9216*2   = 18,874,368 B
  bf16_t* W34t    = (bf16_t*)(ws + 58195968);    // 2048*2048*2   =  8,388,608 B

  // cooperative path needs 2 blocks/CU co-resident (512 blocks on 256 CUs)
  static int coop_blocks_per_cu = -1;
  if (coop_blocks_per_cu < 0) {
    int n = 0;
    if (hipOccupancyMaxActiveBlocksPerMultiprocessor(&n, (const void*)mega, 256, 0) != hipSuccess)
      n = 0;
    coop_blocks_per_cu = n;
  }

  bool coop_done = false;
  if (coop_blocks_per_cu >= 2) {
    void* args[] = { (void*)&x, (void*)&lprev, (void*)&W1, (void*)&b1, (void*)&W2, (void*)&b2,
                     (void*)&W3, (void*)&b3, (void*)&W4, (void*)&b4,
                     (void*)&glimpse, (void*)&A2, (void*)&part1, (void*)&part2,
                     (void*)&W1t, (void*)&W34t, (void*)&out };
    coop_done = (hipLaunchCooperativeKernel((const void*)mega, dim3(512), dim3(256),
                                            args, 0, stream) == hipSuccess);
  }

  if (!coop_done) {
    // fallback: proven 5-kernel pipeline
    fov_conv_kernel<<<5120, 256, 0, stream>>>(x, lprev, glimpse, W1, W3, W4, W1t, W34t);
    gemm_bb<128, 64, 576, 1024, 9216>
        <<<dim3(2, 16, 16), 256, 0, stream>>>(glimpse, W1t, part1);
    fuse_mid<<<2048, 256, 0, stream>>>(part1, b1, lprev, W2, b2, A2);
    gemm_bb<128, 64, 256, 2048, 2048>
        <<<dim3(2, 32, 8), 256, 0, stream>>>(A2, W34t, part2);
    epilogue2<<<2048, 256, 0, stream>>>(part2, b3, b4, out);
  }
}

// Round 4
// 605.570 us; speedup vs baseline: 1.2926x; 1.2926x over previous
//
#include <hip/hip_runtime.h>

typedef __bf16 bf16_t;
typedef __bf16 bf16x8 __attribute__((ext_vector_type(8)));
typedef float f32x4 __attribute__((ext_vector_type(4)));
typedef unsigned short us4 __attribute__((ext_vector_type(4)));
typedef unsigned short us8 __attribute__((ext_vector_type(8)));

#define LO4(v) __builtin_shufflevector(v, v, 0, 1, 2, 3)
#define HI4(v) __builtin_shufflevector(v, v, 4, 5, 6, 7)

// ---------------- foveation unit ----------------
template<int F>
__device__ __forceinline__ void fov_scale(const float* __restrict__ xb,
                                          bf16_t* __restrict__ gb,
                                          int r0, int c0, int base, int count, int kidx)
{
  constexpr float inv = 1.0f / (F * F);
  for (int i = threadIdx.x; i < count; i += 256) {
    const int idx = base + i;              // 0..3071 within this scale (c*1024 + gy*32 + gx)
    const int ch  = idx >> 10;
    const int rem = idx & 1023;
    const int gy  = rem >> 5, gx = rem & 31;
    const float* xc = xb + ch * 50176;
    float sum = 0.0f;
    const int rbase = r0 + gy * F, cbase = c0 + gx * F;
#pragma unroll
    for (int dy = 0; dy < F; ++dy) {
      const int rr = rbase + dy;
      if ((unsigned)rr < 224u) {
#pragma unroll
        for (int dx = 0; dx < F; ++dx) {
          const int cc = cbase + dx;
          if ((unsigned)cc < 224u) sum += xc[rr * 224 + cc];
        }
      }
    }
    gb[kidx * 3072 + idx] = (bf16_t)(sum * inv);
  }
}

__device__ __forceinline__ void fov_unit(const float* __restrict__ x,
                                         const float* __restrict__ l,
                                         bf16_t* __restrict__ g, int u)
{
  const int b = u & 255;
  const int y = u >> 8;       // 7 work partitions weighted by read cost
  const float l0 = l[2 * b], l1 = l[2 * b + 1];
  // match reference exactly: (int)(0.5f * ((l + 1.0f) * 224.0f)), trunc (values >= 0)
  const int st0 = (int)(0.5f * ((l0 + 1.0f) * 224.0f));  // col start
  const int st1 = (int)(0.5f * ((l1 + 1.0f) * 224.0f));  // row start
  const float* xb = x + (size_t)b * 3 * 50176;
  bf16_t* gb = g + (size_t)b * 9216;
  if (y == 0) {
    fov_scale<1>(xb, gb, st1 - 17, st0 - 17, 0, 3072, 0);              // pad = 32/2+1
  } else if (y <= 2) {
    fov_scale<2>(xb, gb, st1 - 33, st0 - 33, (y - 1) * 1536, 1536, 1); // pad = 64/2+1
  } else {
    fov_scale<4>(xb, gb, st1 - 65, st0 - 65, (y - 3) * 768, 768, 2);   // pad = 128/2+1
  }
}

// ---------------- 64x64 fp32 -> bf16 transpose tile ----------------
__device__ __forceinline__ void transpose_tile(const float* __restrict__ src, int srcld,
                                               unsigned short* __restrict__ dst, int dstld,
                                               unsigned short* __restrict__ T)
{
  const int t = threadIdx.x;
#pragma unroll
  for (int it = 0; it < 16; ++it) {
    const int idx = it * 256 + t;        // 0..4095
    const int kk = idx >> 6, nn = idx & 63;   // coalesced along nn
    T[nn * 72 + kk] = __builtin_bit_cast(unsigned short, (bf16_t)src[(size_t)kk * srcld + nn]);
  }
  __syncthreads();
#pragma unroll
  for (int it = 0; it < 2; ++it) {
    const int q = it * 256 + t;          // 0..511
    const int n = q >> 3, kc = (q & 7) * 8;
    *(us8*)(dst + (size_t)n * dstld + kc) = *(const us8*)&T[n * 72 + kc];
  }
}

// ---------------- kernel 1: foveate + weight transpose/convert + counter init ----------------
__global__ __launch_bounds__(256) void fov_conv_kernel(const float* __restrict__ x,
                                                       const float* __restrict__ l,
                                                       bf16_t* __restrict__ g,
                                                       const float* __restrict__ W1,
                                                       const float* __restrict__ W3,
                                                       const float* __restrict__ W4,
                                                       bf16_t* __restrict__ W1t,
                                                       bf16_t* __restrict__ W34t,
                                                       int* __restrict__ ctrs)
{
  __shared__ unsigned short T[64 * 72];
  const int bid = blockIdx.x;
  if (bid == 0 && threadIdx.x < 96) ctrs[threadIdx.x] = 0;   // 32 gemm1 + 64 gemm2 group counters
  if (bid < 1792) {
    fov_unit(x, l, g, bid);
  } else if (bid < 4096) {
    const int cid = bid - 1792;          // 144 ktiles x 16 ntiles
    const int kt = cid >> 4, nt = cid & 15;
    transpose_tile(W1 + (size_t)(kt * 64) * 1024 + nt * 64, 1024,
                   (unsigned short*)W1t + (size_t)(nt * 64) * 9216 + kt * 64, 9216, T);
  } else {
    const int cid = bid - 4096;          // 32 ktiles x 32 ntiles
    const int kt = cid >> 5, nt = cid & 31;
    const int k0 = kt * 64;              // tile never straddles k=1024 (64 | 1024)
    const float* src = (k0 < 1024) ? (W3 + (size_t)k0 * 2048 + nt * 64)
                                   : (W4 + (size_t)(k0 - 1024) * 2048 + nt * 64);
    transpose_tile(src, 2048,
                   (unsigned short*)W34t + (size_t)(nt * 64) * 2048 + k0, 2048, T);
  }
}

// ---------------- split-K bf16 MFMA GEMM body (both operands k-contiguous bf16) ----------------
template<int BM, int BN, int KCHUNK, int NDIM, int KFULL>
__device__ __forceinline__ void gemm_body(const bf16_t* __restrict__ A,
                                          const bf16_t* __restrict__ Bt,
                                          float* __restrict__ part,
                                          int bx, int by, int bz,
                                          unsigned short* __restrict__ sh)
{
  constexpr int WROWS = BM / 4;     // rows per wave
  constexpr int SM = WROWS / 16;    // 16-row subtiles per wave
  constexpr int SN = BN / 16;       // 16-col subtiles
  constexpr int LDA = 36;           // LDS row stride (ushorts): conflict-benign for b64 frag reads
  constexpr int NLA = BM / 64;      // us8 A loads per thread per k-step
  unsigned short* Al = sh;
  unsigned short* Bl = sh + BM * LDA;
  const int t = threadIdx.x;
  const int w = t >> 6, lane = t & 63;
  const int lr = lane & 15, kg = lane >> 4;
  const int bm0 = bx * BM, bn0 = by * BN;
  const int ks0 = bz * KCHUNK;
  const unsigned short* Au = (const unsigned short*)A;
  const unsigned short* Bu = (const unsigned short*)Bt;

  const int bn = t >> 2, bkb = (t & 3) * 8;
  const bool bld = (t < BN * 4);    // wave-uniform (multiple-of-64 cut)

  f32x4 acc[SM][SN] = {};
  us8 pa[NLA], pb;

  // prologue: load k-tile 0 into regs
#pragma unroll
  for (int i = 0; i < NLA; ++i) {
    const int q = t + 256 * i;
    pa[i] = *(const us8*)(Au + (size_t)(bm0 + (q >> 2)) * KFULL + ks0 + (q & 3) * 8);
  }
  if (bld) pb = *(const us8*)(Bu + (size_t)(bn0 + bn) * KFULL + ks0 + bkb);

  for (int k0 = 0; k0 < KCHUNK; k0 += 32) {
    // ---- regs -> LDS ----
#pragma unroll
    for (int i = 0; i < NLA; ++i) {
      const int q = t + 256 * i;
      const int m = q >> 2, kb = (q & 3) * 8;
      *(us4*)(&Al[m * LDA + kb])     = LO4(pa[i]);
      *(us4*)(&Al[m * LDA + kb + 4]) = HI4(pa[i]);
    }
    if (bld) {
      *(us4*)(&Bl[bn * LDA + bkb])     = LO4(pb);
      *(us4*)(&Bl[bn * LDA + bkb + 4]) = HI4(pb);
    }
    __syncthreads();
    // ---- prefetch next k-tile into regs (overlaps with frag reads + MFMA) ----
    if (k0 + 32 < KCHUNK) {
      const int knext = ks0 + k0 + 32;
#pragma unroll
      for (int i = 0; i < NLA; ++i) {
        const int q = t + 256 * i;
        pa[i] = *(const us8*)(Au + (size_t)(bm0 + (q >> 2)) * KFULL + knext + (q & 3) * 8);
      }
      if (bld) pb = *(const us8*)(Bu + (size_t)(bn0 + bn) * KFULL + knext + bkb);
    }
    // ---- fragments (A[m=lr][k=kg*8+j], B[n=lr][k=kg*8+j]) + MFMA ----
    bf16x8 af[SM], bfr[SN];
#pragma unroll
    for (int sm = 0; sm < SM; ++sm) {
      const unsigned short* p = &Al[(w * WROWS + sm * 16 + lr) * LDA + kg * 8];
      us4 x0 = *(const us4*)p;
      us4 x1 = *(const us4*)(p + 4);
      af[sm] = __builtin_bit_cast(bf16x8, __builtin_shufflevector(x0, x1, 0, 1, 2, 3, 4, 5, 6, 7));
    }
#pragma unroll
    for (int sn = 0; sn < SN; ++sn) {
      const unsigned short* p = &Bl[(sn * 16 + lr) * LDA + kg * 8];
      us4 x0 = *(const us4*)p;
      us4 x1 = *(const us4*)(p + 4);
      bfr[sn] = __builtin_bit_cast(bf16x8, __builtin_shufflevector(x0, x1, 0, 1, 2, 3, 4, 5, 6, 7));
    }
#pragma unroll
    for (int sm = 0; sm < SM; ++sm)
#pragma unroll
      for (int sn = 0; sn < SN; ++sn)
        acc[sm][sn] = __builtin_amdgcn_mfma_f32_16x16x32_bf16(af[sm], bfr[sn], acc[sm][sn], 0, 0, 0);
    __syncthreads();
  }
  // ---- write fp32 partials (C/D layout: col=lr, row=kg*4+r) ----
  float* outp = part + (size_t)bz * ((size_t)256 * NDIM);
#pragma unroll
  for (int sm = 0; sm < SM; ++sm)
#pragma unroll
    for (int sn = 0; sn < SN; ++sn)
#pragma unroll
      for (int r = 0; r < 4; ++r) {
        const int gm = bm0 + w * WROWS + sm * 16 + kg * 4 + r;
        const int gn = bn0 + sn * 16 + lr;
        outp[(size_t)gm * NDIM + gn] = acc[sm][sn][r];
      }
}

// ---------------- GEMM + split-K fixup epilogue (last block of each tile group reduces) ----------------
// EPI==1: GEMM1. dst = A2 bf16 [256x2048]; bias0=b1; l-blocks (by==NDIM/BN) do relu(lprev@W2+b2)
//         into A2 cols 1024..2047 (bias1=b2).
// EPI==2: GEMM2. dst = out fp32 [256x2048]; adds bias0+bias1 = b3+b4.
template<int BM, int BN, int KCHUNK, int NDIM, int KFULL, int NZ, int EPI>
__global__ __launch_bounds__(256) void gemm_fused(const bf16_t* __restrict__ A,
                                                  const bf16_t* __restrict__ Bt,
                                                  float* __restrict__ part,
                                                  const float* __restrict__ bias0,
                                                  const float* __restrict__ bias1,
                                                  const float* __restrict__ lprev,
                                                  const float* __restrict__ W2,
                                                  void* __restrict__ dst,
                                                  int* __restrict__ ctr)
{
  const int bx = blockIdx.x, by = blockIdx.y, bz = blockIdx.z;
  const int t = threadIdx.x;

  if (EPI == 1 && by == NDIM / BN) {     // l_out path: A2[:, 1024:2048] = relu(lprev@W2+b2)
    if (bz != 0) return;
#pragma unroll 4
    for (int e = 0; e < BM * 1024 / 256; ++e) {
      const int lin = e * 256 + t;
      const int row = bx * BM + (lin >> 10), col = lin & 1023;
      const float s = fmaf(lprev[2 * row], W2[col],
                      fmaf(lprev[2 * row + 1], W2[1024 + col], bias1[col]));
      ((bf16_t*)dst)[(size_t)row * 2048 + 1024 + col] = (bf16_t)fmaxf(s, 0.0f);
    }
    return;
  }

  __shared__ unsigned short sh[(BM + BN) * 36];
  __shared__ int lastflag;
  gemm_body<BM, BN, KCHUNK, NDIM, KFULL>(A, Bt, part, bx, by, bz, sh);

  // canonical fixup handshake: release-fence + barrier, one thread takes the ticket
  __threadfence();
  __syncthreads();
  if (t == 0)
    lastflag = (atomicAdd(&ctr[by * 2 + bx], 1) == NZ - 1);
  __syncthreads();
  if (!lastflag) return;
  __threadfence();   // acquire side: invalidate stale cached lines before reading partials

  // last block: reduce NZ partials for this (bx,by) tile, bias + relu, write dst
  const int bm0 = bx * BM, bn0 = by * BN;
#pragma unroll
  for (int e = 0; e < BM * BN / 256; ++e) {
    const int lin = e * 256 + t;
    const int r = lin >> 6, c = lin & (BN - 1);   // BN==64: coalesced along c
    const int gm = bm0 + r, gn = bn0 + c;
    float s = (EPI == 1) ? bias0[gn] : bias0[gn] + bias1[gn];
    const volatile float* p = part + (size_t)gm * NDIM + gn;   // L1-bypass (cross-XCD partials)
#pragma unroll
    for (int z = 0; z < NZ; ++z) s += p[(size_t)z * 256 * NDIM];
    s = fmaxf(s, 0.0f);
    if (EPI == 1) ((bf16_t*)dst)[(size_t)gm * 2048 + gn] = (bf16_t)s;
    else          ((float*)dst)[(size_t)gm * 2048 + gn] = s;
  }
}

extern "C" void kernel_launch(void* const* d_in, const int* in_sizes, int n_in,
                              void* d_out, int out_size, void* d_ws, size_t ws_size,
                              hipStream_t stream)
{
  const float* x     = (const float*)d_in[0];
  const float* lprev = (const float*)d_in[1];
  const float* W1    = (const float*)d_in[2];   // (9216, 1024)
  const float* b1    = (const float*)d_in[3];
  const float* W2    = (const float*)d_in[4];   // (2, 1024)
  const float* b2    = (const float*)d_in[5];
  const float* W3    = (const float*)d_in[6];   // (1024, 2048)
  const float* b3    = (const float*)d_in[7];
  const float* W4    = (const float*)d_in[8];   // (1024, 2048)
  const float* b4    = (const float*)d_in[9];
  float* out = (float*)d_out;

  // workspace layout (all 16B aligned), total ~66.6 MB
  char* ws = (char*)d_ws;
  bf16_t* glimpse = (bf16_t*)ws;                 // 256*9216*2    =  4,718,592 B
  bf16_t* A2      = (bf16_t*)(ws + 4718592);     // 256*2048*2    =  1,048,576 B
  float*  part1   = (float*)(ws + 5767168);      // 16*256*1024*4 = 16,777,216 B
  float*  part2   = (float*)(ws + 22544384);     // 8*256*2048*4  = 16,777,216 B
  bf16_t* W1t     = (bf16_t*)(ws + 39321600);    // 1024*9216*2   = 18,874,368 B
  bf16_t* W34t    = (bf16_t*)(ws + 58195968);    // 2048*2048*2   =  8,388,608 B
  int*    ctrs    = (int*)(ws + 66584576);       // 96 ints (32 gemm1 + 64 gemm2 groups)

  // kernel 1: foveation (1792) + W1 transpose (2304) + W34 transpose (1024) + ctr init
  fov_conv_kernel<<<5120, 256, 0, stream>>>(x, lprev, glimpse, W1, W3, W4, W1t, W34t, ctrs);
  // kernel 2: GEMM1 M=256,N=1024,K=9216; 128x64 tiles, splitK=16; fixup writes A2[:, :1024];
  //           by==16 blocks (bz==0) write A2[:, 1024:] = relu(lprev@W2+b2)
  gemm_fused<128, 64, 576, 1024, 9216, 16, 1>
      <<<dim3(2, 17, 16), 256, 0, stream>>>(glimpse, W1t, part1, b1, b2, lprev, W2, A2, ctrs);
  // kernel 3: GEMM2 M=256,N=2048,K=2048; 128x64 tiles, splitK=8; fixup writes out = relu(.+b3+b4)
  gemm_fused<128, 64, 256, 2048, 2048, 8, 2>
      <<<dim3(2, 32, 8), 256, 0, stream>>>(A2, W34t, part2, b3, b4, nullptr, nullptr, out, ctrs + 32);
}

// Round 6
// 300.277 us; speedup vs baseline: 2.6068x; 2.0167x over previous
//
#include <hip/hip_runtime.h>

typedef __bf16 bf16_t;
typedef __bf16 bf16x8 __attribute__((ext_vector_type(8)));
typedef float f32x4 __attribute__((ext_vector_type(4)));
typedef unsigned short us4 __attribute__((ext_vector_type(4)));
typedef unsigned short us8 __attribute__((ext_vector_type(8)));

#define LO4(v) __builtin_shufflevector(v, v, 0, 1, 2, 3)
#define HI4(v) __builtin_shufflevector(v, v, 4, 5, 6, 7)

// ---------------- foveation ----------------
// Output layout: glimpse[b, kidx*3072 + ch*1024 + gy*32 + gx]
// scale k patch: rows r0+F*gy+dy, cols c0+F*gx+dx, OOB = 0 (reference zero-pads).

// scale 1: direct coalesced loads (1 load/output)
__device__ __forceinline__ void fov_s1(const float* __restrict__ xb,
                                       bf16_t* __restrict__ gb, int r0, int c0)
{
  for (int i = threadIdx.x; i < 3072; i += 256) {
    const int ch = i >> 10;
    const int rem = i & 1023;
    const int gy = rem >> 5, gx = rem & 31;
    const int rr = r0 + gy, cc = c0 + gx;
    float v = 0.0f;
    if ((unsigned)rr < 224u && (unsigned)cc < 224u) v = xb[ch * 50176 + rr * 224 + cc];
    gb[i] = (bf16_t)v;
  }
}

// scale 2, one channel: stage 64x64 patch in LDS (coalesced), pool 2x2 -> 32x32
__device__ __forceinline__ void fov_s2(const float* __restrict__ xc,
                                       bf16_t* __restrict__ gc,   // -> gb + 3072 + ch*1024
                                       int r0, int c0, float* __restrict__ S)
{
  const int t = threadIdx.x;
#pragma unroll
  for (int i = 0; i < 16; ++i) {
    const int lin = i * 256 + t;
    const int row = lin >> 6, col = lin & 63;          // coalesced along col
    const int rr = r0 + row, cc = c0 + col;
    float v = 0.0f;
    if ((unsigned)rr < 224u && (unsigned)cc < 224u) v = xc[rr * 224 + cc];
    S[row * 68 + col] = v;
  }
  __syncthreads();
#pragma unroll
  for (int i = 0; i < 4; ++i) {
    const int o = i * 256 + t;                         // 0..1023
    const int gy = o >> 5, gx = o & 31;
    float sum = 0.0f;
#pragma unroll
    for (int dy = 0; dy < 2; ++dy)
#pragma unroll
      for (int dx = 0; dx < 2; ++dx)
        sum += S[(gy * 2 + dy) * 68 + gx * 2 + dx];
    gc[o] = (bf16_t)(sum * 0.25f);
  }
}

// scale 4, one channel, one half (64 patch rows): stage 64x128 in LDS, pool 4x4 -> 16x32
__device__ __forceinline__ void fov_s4(const float* __restrict__ xc,
                                       bf16_t* __restrict__ gc,   // -> gb + 6144 + ch*1024
                                       int r0, int c0, int h, float* __restrict__ S)
{
  const int t = threadIdx.x;
#pragma unroll
  for (int i = 0; i < 32; ++i) {
    const int lin = i * 256 + t;
    const int row = lin >> 7, col = lin & 127;         // coalesced along col
    const int rr = r0 + h * 64 + row, cc = c0 + col;
    float v = 0.0f;
    if ((unsigned)rr < 224u && (unsigned)cc < 224u) v = xc[rr * 224 + cc];
    S[row * 132 + col] = v;
  }
  __syncthreads();
#pragma unroll
  for (int i = 0; i < 2; ++i) {
    const int o = i * 256 + t;                         // 0..511
    const int gyl = o >> 5, gx = o & 31;               // local gy 0..15
    float sum = 0.0f;
#pragma unroll
    for (int dy = 0; dy < 4; ++dy)
#pragma unroll
      for (int dx = 0; dx < 4; ++dx)
        sum += S[(gyl * 4 + dy) * 132 + gx * 4 + dx];
    gc[(h * 16 + gyl) * 32 + gx] = (bf16_t)(sum * 0.0625f);
  }
}

// 10 units per batch: y=0 scale1 | y=1..3 scale2 ch=y-1 | y=4..9 scale4 ch=(y-4)>>1, half=(y-4)&1
__device__ __forceinline__ void fov_unit(const float* __restrict__ x,
                                         const float* __restrict__ l,
                                         bf16_t* __restrict__ g, int u,
                                         float* __restrict__ S)
{
  const int b = u & 255;
  const int y = u >> 8;
  const float l0 = l[2 * b], l1 = l[2 * b + 1];
  // match reference exactly: (int)(0.5f * ((l + 1.0f) * 224.0f)), trunc (values >= 0)
  const int st0 = (int)(0.5f * ((l0 + 1.0f) * 224.0f));  // col start
  const int st1 = (int)(0.5f * ((l1 + 1.0f) * 224.0f));  // row start
  const float* xb = x + (size_t)b * 3 * 50176;
  bf16_t* gb = g + (size_t)b * 9216;
  if (y == 0) {
    fov_s1(xb, gb, st1 - 17, st0 - 17);                                  // pad = 32/2+1
  } else if (y <= 3) {
    const int ch = y - 1;
    fov_s2(xb + ch * 50176, gb + 3072 + ch * 1024, st1 - 33, st0 - 33, S); // pad = 64/2+1
  } else {
    const int ch = (y - 4) >> 1, h = (y - 4) & 1;
    fov_s4(xb + ch * 50176, gb + 6144 + ch * 1024, st1 - 65, st0 - 65, h, S); // pad = 128/2+1
  }
}

// ---------------- 64x64 fp32 -> bf16 transpose tile ----------------
__device__ __forceinline__ void transpose_tile(const float* __restrict__ src, int srcld,
                                               unsigned short* __restrict__ dst, int dstld,
                                               unsigned short* __restrict__ T)
{
  const int t = threadIdx.x;
#pragma unroll
  for (int it = 0; it < 16; ++it) {
    const int idx = it * 256 + t;        // 0..4095
    const int kk = idx >> 6, nn = idx & 63;   // coalesced along nn
    T[nn * 72 + kk] = __builtin_bit_cast(unsigned short, (bf16_t)src[(size_t)kk * srcld + nn]);
  }
  __syncthreads();
#pragma unroll
  for (int it = 0; it < 2; ++it) {
    const int q = it * 256 + t;          // 0..511
    const int n = q >> 3, kc = (q & 7) * 8;
    *(us8*)(dst + (size_t)n * dstld + kc) = *(const us8*)&T[n * 72 + kc];
  }
}

// ---------------- kernel 1: foveate (2560) + weight transpose/convert (3328) ----------------
__global__ __launch_bounds__(256) void fov_conv_kernel(const float* __restrict__ x,
                                                       const float* __restrict__ l,
                                                       bf16_t* __restrict__ g,
                                                       const float* __restrict__ W1,
                                                       const float* __restrict__ W3,
                                                       const float* __restrict__ W4,
                                                       bf16_t* __restrict__ W1t,
                                                       bf16_t* __restrict__ W34t)
{
  __shared__ float S[64 * 132];          // 33792 B; unioned: transpose uses it as ushort[64*72]
  const int bid = blockIdx.x;
  if (bid < 2560) {
    fov_unit(x, l, g, bid, S);
  } else if (bid < 4864) {
    const int cid = bid - 2560;          // 144 ktiles x 16 ntiles
    const int kt = cid >> 4, nt = cid & 15;
    transpose_tile(W1 + (size_t)(kt * 64) * 1024 + nt * 64, 1024,
                   (unsigned short*)W1t + (size_t)(nt * 64) * 9216 + kt * 64, 9216,
                   (unsigned short*)S);
  } else {
    const int cid = bid - 4864;          // 32 ktiles x 32 ntiles
    const int kt = cid >> 5, nt = cid & 31;
    const int k0 = kt * 64;              // tile never straddles k=1024 (64 | 1024)
    const float* src = (k0 < 1024) ? (W3 + (size_t)k0 * 2048 + nt * 64)
                                   : (W4 + (size_t)(k0 - 1024) * 2048 + nt * 64);
    transpose_tile(src, 2048,
                   (unsigned short*)W34t + (size_t)(nt * 64) * 2048 + k0, 2048,
                   (unsigned short*)S);
  }
}

// ---------------- split-K bf16 MFMA GEMM (both operands k-contiguous bf16) ----------------
template<int BM, int BN, int KCHUNK, int NDIM, int KFULL>
__global__ __launch_bounds__(256) void gemm_bb(const bf16_t* __restrict__ A,
                                               const bf16_t* __restrict__ Bt,
                                               float* __restrict__ part)
{
  constexpr int WROWS = BM / 4;     // rows per wave
  constexpr int SM = WROWS / 16;    // 16-row subtiles per wave
  constexpr int SN = BN / 16;       // 16-col subtiles
  constexpr int LDA = 36;           // LDS row stride (ushorts): conflict-benign for b64 frag reads
  constexpr int NLA = BM / 64;      // us8 A loads per thread per k-step
  __shared__ unsigned short Al[BM * LDA];
  __shared__ unsigned short Bl[BN * LDA];
  const int t = threadIdx.x;
  const int w = t >> 6, lane = t & 63;
  const int lr = lane & 15, kg = lane >> 4;
  const int bm0 = blockIdx.x * BM, bn0 = blockIdx.y * BN;
  const int ks0 = blockIdx.z * KCHUNK;
  const unsigned short* Au = (const unsigned short*)A;
  const unsigned short* Bu = (const unsigned short*)Bt;

  const int bn = t >> 2, bkb = (t & 3) * 8;
  const bool bld = (t < BN * 4);    // wave-uniform (multiple-of-64 cut)

  f32x4 acc[SM][SN] = {};
  us8 pa[NLA], pb;

  // prologue: load k-tile 0 into regs
#pragma unroll
  for (int i = 0; i < NLA; ++i) {
    const int q = t + 256 * i;
    pa[i] = *(const us8*)(Au + (size_t)(bm0 + (q >> 2)) * KFULL + ks0 + (q & 3) * 8);
  }
  if (bld) pb = *(const us8*)(Bu + (size_t)(bn0 + bn) * KFULL + ks0 + bkb);

  for (int k0 = 0; k0 < KCHUNK; k0 += 32) {
    // ---- regs -> LDS ----
#pragma unroll
    for (int i = 0; i < NLA; ++i) {
      const int q = t + 256 * i;
      const int m = q >> 2, kb = (q & 3) * 8;
      *(us4*)(&Al[m * LDA + kb])     = LO4(pa[i]);
      *(us4*)(&Al[m * LDA + kb + 4]) = HI4(pa[i]);
    }
    if (bld) {
      *(us4*)(&Bl[bn * LDA + bkb])     = LO4(pb);
      *(us4*)(&Bl[bn * LDA + bkb + 4]) = HI4(pb);
    }
    __syncthreads();
    // ---- prefetch next k-tile into regs (overlaps with frag reads + MFMA) ----
    if (k0 + 32 < KCHUNK) {
      const int knext = ks0 + k0 + 32;
#pragma unroll
      for (int i = 0; i < NLA; ++i) {
        const int q = t + 256 * i;
        pa[i] = *(const us8*)(Au + (size_t)(bm0 + (q >> 2)) * KFULL + knext + (q & 3) * 8);
      }
      if (bld) pb = *(const us8*)(Bu + (size_t)(bn0 + bn) * KFULL + knext + bkb);
    }
    // ---- fragments (A[m=lr][k=kg*8+j], B[n=lr][k=kg*8+j]) + MFMA ----
    bf16x8 af[SM], bfr[SN];
#pragma unroll
    for (int sm = 0; sm < SM; ++sm) {
      const unsigned short* p = &Al[(w * WROWS + sm * 16 + lr) * LDA + kg * 8];
      us4 x0 = *(const us4*)p;
      us4 x1 = *(const us4*)(p + 4);
      af[sm] = __builtin_bit_cast(bf16x8, __builtin_shufflevector(x0, x1, 0, 1, 2, 3, 4, 5, 6, 7));
    }
#pragma unroll
    for (int sn = 0; sn < SN; ++sn) {
      const unsigned short* p = &Bl[(sn * 16 + lr) * LDA + kg * 8];
      us4 x0 = *(const us4*)p;
      us4 x1 = *(const us4*)(p + 4);
      bfr[sn] = __builtin_bit_cast(bf16x8, __builtin_shufflevector(x0, x1, 0, 1, 2, 3, 4, 5, 6, 7));
    }
#pragma unroll
    for (int sm = 0; sm < SM; ++sm)
#pragma unroll
      for (int sn = 0; sn < SN; ++sn)
        acc[sm][sn] = __builtin_amdgcn_mfma_f32_16x16x32_bf16(af[sm], bfr[sn], acc[sm][sn], 0, 0, 0);
    __syncthreads();
  }
  // ---- write fp32 partials (C/D layout: col=lr, row=kg*4+r) ----
  float* outp = part + (size_t)blockIdx.z * ((size_t)256 * NDIM);
#pragma unroll
  for (int sm = 0; sm < SM; ++sm)
#pragma unroll
    for (int sn = 0; sn < SN; ++sn)
#pragma unroll
      for (int r = 0; r < 4; ++r) {
        const int gm = bm0 + w * WROWS + sm * 16 + kg * 4 + r;
        const int gn = bn0 + sn * 16 + lr;
        outp[(size_t)gm * NDIM + gn] = acc[sm][sn][r];
      }
}

// ---------------- reduce GEMM1 partials (16) + bias + relu -> bf16; also l_out path ----------------
__global__ __launch_bounds__(256) void fuse_mid(const float* __restrict__ part1,
                                                const float* __restrict__ b1,
                                                const float* __restrict__ lprev,
                                                const float* __restrict__ W2,
                                                const float* __restrict__ b2,
                                                bf16_t* __restrict__ A2)
{
  const int idx = blockIdx.x * 256 + threadIdx.x;  // 0..524287; block-uniform branch (col chunk of 256)
  const int row = idx >> 11, col = idx & 2047;
  float s;
  if (col < 1024) {
    s = b1[col];
#pragma unroll
    for (int i = 0; i < 16; ++i) s += part1[i * 262144 + row * 1024 + col];
  } else {
    const int n = col - 1024;
    s = fmaf(lprev[2 * row], W2[n], fmaf(lprev[2 * row + 1], W2[1024 + n], b2[n]));
  }
  A2[idx] = (bf16_t)fmaxf(s, 0.0f);
}

// ---------------- reduce GEMM2 partials (8) + (b3+b4) + relu -> fp32 out ----------------
__global__ __launch_bounds__(256) void epilogue2(const float* __restrict__ part2,
                                                 const float* __restrict__ b3,
                                                 const float* __restrict__ b4,
                                                 float* __restrict__ out)
{
  const int idx = blockIdx.x * 256 + threadIdx.x;  // 0..524287
  const int col = idx & 2047;
  float s = b3[col] + b4[col];
#pragma unroll
  for (int i = 0; i < 8; ++i) s += part2[i * 524288 + idx];
  out[idx] = fmaxf(s, 0.0f);
}

extern "C" void kernel_launch(void* const* d_in, const int* in_sizes, int n_in,
                              void* d_out, int out_size, void* d_ws, size_t ws_size,
                              hipStream_t stream)
{
  const float* x     = (const float*)d_in[0];
  const float* lprev = (const float*)d_in[1];
  const float* W1    = (const float*)d_in[2];   // (9216, 1024)
  const float* b1    = (const float*)d_in[3];
  const float* W2    = (const float*)d_in[4];   // (2, 1024)
  const float* b2    = (const float*)d_in[5];
  const float* W3    = (const float*)d_in[6];   // (1024, 2048)
  const float* b3    = (const float*)d_in[7];
  const float* W4    = (const float*)d_in[8];   // (1024, 2048)
  const float* b4    = (const float*)d_in[9];
  float* out = (float*)d_out;

  // workspace layout (all 16B aligned), total ~66.6 MB
  char* ws = (char*)d_ws;
  bf16_t* glimpse = (bf16_t*)ws;                 // 256*9216*2    =  4,718,592 B
  bf16_t* A2      = (bf16_t*)(ws + 4718592);     // 256*2048*2    =  1,048,576 B
  float*  part1   = (float*)(ws + 5767168);      // 16*256*1024*4 = 16,777,216 B
  float*  part2   = (float*)(ws + 22544384);     // 8*256*2048*4  = 16,777,216 B
  bf16_t* W1t     = (bf16_t*)(ws + 39321600);    // 1024*9216*2   = 18,874,368 B
  bf16_t* W34t    = (bf16_t*)(ws + 58195968);    // 2048*2048*2   =  8,388,608 B

  // kernel 1: foveation (2560 = 256 batches x 10 units) + W1 transpose (2304) + W34 transpose (1024)
  fov_conv_kernel<<<5888, 256, 0, stream>>>(x, lprev, glimpse, W1, W3, W4, W1t, W34t);
  // kernel 2: GEMM1 M=256,N=1024,K=9216; 128x64 tiles, splitK=16 -> 512 blocks (2/CU)
  gemm_bb<128, 64, 576, 1024, 9216>
      <<<dim3(2, 16, 16), 256, 0, stream>>>(glimpse, W1t, part1);
  // kernel 3: reduce + bias + relu -> A2
  fuse_mid<<<2048, 256, 0, stream>>>(part1, b1, lprev, W2, b2, A2);
  // kernel 4: GEMM2 M=256,N=2048,K=2048; 128x64 tiles, splitK=8 -> 512 blocks
  gemm_bb<128, 64, 256, 2048, 2048>
      <<<dim3(2, 32, 8), 256, 0, stream>>>(A2, W34t, part2);
  // kernel 5: reduce + (b3+b4) + relu -> out
  epilogue2<<<2048, 256, 0, stream>>>(part2, b3, b4, out);
}

// Round 7
// 285.898 us; speedup vs baseline: 2.7379x; 1.0503x over previous
//
#include <hip/hip_runtime.h>

typedef __bf16 bf16_t;
typedef __bf16 bf16x8 __attribute__((ext_vector_type(8)));
typedef float f32x4 __attribute__((ext_vector_type(4)));
typedef unsigned short us4 __attribute__((ext_vector_type(4)));
typedef unsigned short us8 __attribute__((ext_vector_type(8)));

#define LO4(v) __builtin_shufflevector(v, v, 0, 1, 2, 3)
#define HI4(v) __builtin_shufflevector(v, v, 4, 5, 6, 7)

// ---------------- foveation (round-1 proven version) ----------------
// glimpse[b, (k*3+c)*1024 + gy*32 + gx] = avgpool_F( x[b,c, st1-pad+gy*F+dy, st0-pad+gx*F+dx] )
template<int F>
__device__ __forceinline__ void fov_scale(const float* __restrict__ xb,
                                          bf16_t* __restrict__ gb,
                                          int r0, int c0, int base, int count, int kidx)
{
  constexpr float inv = 1.0f / (F * F);
  for (int i = threadIdx.x; i < count; i += 256) {
    const int idx = base + i;              // 0..3071 within this scale (c*1024 + gy*32 + gx)
    const int ch  = idx >> 10;
    const int rem = idx & 1023;
    const int gy  = rem >> 5, gx = rem & 31;
    const float* xc = xb + ch * 50176;
    float sum = 0.0f;
    const int rbase = r0 + gy * F, cbase = c0 + gx * F;
#pragma unroll
    for (int dy = 0; dy < F; ++dy) {
      const int rr = rbase + dy;
      if ((unsigned)rr < 224u) {
#pragma unroll
        for (int dx = 0; dx < F; ++dx) {
          const int cc = cbase + dx;
          if ((unsigned)cc < 224u) sum += xc[rr * 224 + cc];
        }
      }
    }
    gb[kidx * 3072 + idx] = (bf16_t)(sum * inv);
  }
}

__device__ __forceinline__ void fov_unit(const float* __restrict__ x,
                                         const float* __restrict__ l,
                                         bf16_t* __restrict__ g, int u)
{
  const int b = u & 255;
  const int y = u >> 8;       // 7 work partitions weighted by read cost
  const float l0 = l[2 * b], l1 = l[2 * b + 1];
  // match reference exactly: (int)(0.5f * ((l + 1.0f) * 224.0f)), trunc (values >= 0)
  const int st0 = (int)(0.5f * ((l0 + 1.0f) * 224.0f));  // col start
  const int st1 = (int)(0.5f * ((l1 + 1.0f) * 224.0f));  // row start
  const float* xb = x + (size_t)b * 3 * 50176;
  bf16_t* gb = g + (size_t)b * 9216;
  if (y == 0) {
    fov_scale<1>(xb, gb, st1 - 17, st0 - 17, 0, 3072, 0);              // pad = 32/2+1
  } else if (y <= 2) {
    fov_scale<2>(xb, gb, st1 - 33, st0 - 33, (y - 1) * 1536, 1536, 1); // pad = 64/2+1
  } else {
    fov_scale<4>(xb, gb, st1 - 65, st0 - 65, (y - 3) * 768, 768, 2);   // pad = 128/2+1
  }
}

// ---------------- 64x64 fp32 -> bf16 transpose tile (float4 reads) ----------------
// src: tile origin of [64 k][64 n] fp32, row stride srcld (multiple of 4).
// dst: tile origin of [64 n][64 k] bf16 (as ushort), row stride dstld.
__device__ __forceinline__ void transpose_tile(const float* __restrict__ src, int srcld,
                                               unsigned short* __restrict__ dst, int dstld,
                                               unsigned short* __restrict__ T)
{
  const int t = threadIdx.x;
#pragma unroll
  for (int it = 0; it < 4; ++it) {
    const int lin = it * 256 + t;             // 0..1023 float4-quads
    const int kk = lin >> 4, nn = (lin & 15) * 4;   // coalesced f4 along nn
    const float4 v = *(const float4*)(src + (size_t)kk * srcld + nn);
    T[(nn + 0) * 72 + kk] = __builtin_bit_cast(unsigned short, (bf16_t)v.x);
    T[(nn + 1) * 72 + kk] = __builtin_bit_cast(unsigned short, (bf16_t)v.y);
    T[(nn + 2) * 72 + kk] = __builtin_bit_cast(unsigned short, (bf16_t)v.z);
    T[(nn + 3) * 72 + kk] = __builtin_bit_cast(unsigned short, (bf16_t)v.w);
  }
  __syncthreads();
#pragma unroll
  for (int it = 0; it < 2; ++it) {
    const int q = it * 256 + t;          // 0..511
    const int n = q >> 3, kc = (q & 7) * 8;
    *(us8*)(dst + (size_t)n * dstld + kc) = *(const us8*)&T[n * 72 + kc];
  }
}

// ---------------- kernel 1: foveate (1792) + weight transpose/convert (3328) ----------------
__global__ __launch_bounds__(256) void fov_conv_kernel(const float* __restrict__ x,
                                                       const float* __restrict__ l,
                                                       bf16_t* __restrict__ g,
                                                       const float* __restrict__ W1,
                                                       const float* __restrict__ W3,
                                                       const float* __restrict__ W4,
                                                       bf16_t* __restrict__ W1t,
                                                       bf16_t* __restrict__ W34t)
{
  __shared__ unsigned short T[64 * 72];
  const int bid = blockIdx.x;
  if (bid < 1792) {
    fov_unit(x, l, g, bid);
  } else if (bid < 4096) {
    const int cid = bid - 1792;          // 144 ktiles x 16 ntiles
    const int kt = cid >> 4, nt = cid & 15;
    transpose_tile(W1 + (size_t)(kt * 64) * 1024 + nt * 64, 1024,
                   (unsigned short*)W1t + (size_t)(nt * 64) * 9216 + kt * 64, 9216, T);
  } else {
    const int cid = bid - 4096;          // 32 ktiles x 32 ntiles
    const int kt = cid >> 5, nt = cid & 31;
    const int k0 = kt * 64;              // tile never straddles k=1024 (64 | 1024)
    const float* src = (k0 < 1024) ? (W3 + (size_t)k0 * 2048 + nt * 64)
                                   : (W4 + (size_t)(k0 - 1024) * 2048 + nt * 64);
    transpose_tile(src, 2048,
                   (unsigned short*)W34t + (size_t)(nt * 64) * 2048 + k0, 2048, T);
  }
}

// ---------------- split-K bf16 MFMA GEMM (both operands k-contiguous bf16) ----------------
template<int BM, int BN, int KCHUNK, int NDIM, int KFULL>
__global__ __launch_bounds__(256) void gemm_bb(const bf16_t* __restrict__ A,
                                               const bf16_t* __restrict__ Bt,
                                               float* __restrict__ part)
{
  constexpr int WROWS = BM / 4;     // rows per wave
  constexpr int SM = WROWS / 16;    // 16-row subtiles per wave
  constexpr int SN = BN / 16;       // 16-col subtiles
  constexpr int LDA = 36;           // LDS row stride (ushorts): conflict-benign for b64 frag reads
  constexpr int NLA = BM / 64;      // us8 A loads per thread per k-step
  __shared__ unsigned short Al[BM * LDA];
  __shared__ unsigned short Bl[BN * LDA];
  const int t = threadIdx.x;
  const int w = t >> 6, lane = t & 63;
  const int lr = lane & 15, kg = lane >> 4;
  const int bm0 = blockIdx.x * BM, bn0 = blockIdx.y * BN;
  const int ks0 = blockIdx.z * KCHUNK;
  const unsigned short* Au = (const unsigned short*)A;
  const unsigned short* Bu = (const unsigned short*)Bt;

  const int bn = t >> 2, bkb = (t & 3) * 8;
  const bool bld = (t < BN * 4);    // wave-uniform (multiple-of-64 cut)

  f32x4 acc[SM][SN] = {};
  us8 pa[NLA], pb;

  // prologue: load k-tile 0 into regs
#pragma unroll
  for (int i = 0; i < NLA; ++i) {
    const int q = t + 256 * i;
    pa[i] = *(const us8*)(Au + (size_t)(bm0 + (q >> 2)) * KFULL + ks0 + (q & 3) * 8);
  }
  if (bld) pb = *(const us8*)(Bu + (size_t)(bn0 + bn) * KFULL + ks0 + bkb);

  for (int k0 = 0; k0 < KCHUNK; k0 += 32) {
    // ---- regs -> LDS ----
#pragma unroll
    for (int i = 0; i < NLA; ++i) {
      const int q = t + 256 * i;
      const int m = q >> 2, kb = (q & 3) * 8;
      *(us4*)(&Al[m * LDA + kb])     = LO4(pa[i]);
      *(us4*)(&Al[m * LDA + kb + 4]) = HI4(pa[i]);
    }
    if (bld) {
      *(us4*)(&Bl[bn * LDA + bkb])     = LO4(pb);
      *(us4*)(&Bl[bn * LDA + bkb + 4]) = HI4(pb);
    }
    __syncthreads();
    // ---- prefetch next k-tile into regs (overlaps with frag reads + MFMA) ----
    if (k0 + 32 < KCHUNK) {
      const int knext = ks0 + k0 + 32;
#pragma unroll
      for (int i = 0; i < NLA; ++i) {
        const int q = t + 256 * i;
        pa[i] = *(const us8*)(Au + (size_t)(bm0 + (q >> 2)) * KFULL + knext + (q & 3) * 8);
      }
      if (bld) pb = *(const us8*)(Bu + (size_t)(bn0 + bn) * KFULL + knext + bkb);
    }
    // ---- fragments (A[m=lr][k=kg*8+j], B[n=lr][k=kg*8+j]) + MFMA ----
    bf16x8 af[SM], bfr[SN];
#pragma unroll
    for (int sm = 0; sm < SM; ++sm) {
      const unsigned short* p = &Al[(w * WROWS + sm * 16 + lr) * LDA + kg * 8];
      us4 x0 = *(const us4*)p;
      us4 x1 = *(const us4*)(p + 4);
      af[sm] = __builtin_bit_cast(bf16x8, __builtin_shufflevector(x0, x1, 0, 1, 2, 3, 4, 5, 6, 7));
    }
#pragma unroll
    for (int sn = 0; sn < SN; ++sn) {
      const unsigned short* p = &Bl[(sn * 16 + lr) * LDA + kg * 8];
      us4 x0 = *(const us4*)p;
      us4 x1 = *(const us4*)(p + 4);
      bfr[sn] = __builtin_bit_cast(bf16x8, __builtin_shufflevector(x0, x1, 0, 1, 2, 3, 4, 5, 6, 7));
    }
#pragma unroll
    for (int sm = 0; sm < SM; ++sm)
#pragma unroll
      for (int sn = 0; sn < SN; ++sn)
        acc[sm][sn] = __builtin_amdgcn_mfma_f32_16x16x32_bf16(af[sm], bfr[sn], acc[sm][sn], 0, 0, 0);
    __syncthreads();
  }
  // ---- write fp32 partials (C/D layout: col=lr, row=kg*4+r) ----
  float* outp = part + (size_t)blockIdx.z * ((size_t)256 * NDIM);
#pragma unroll
  for (int sm = 0; sm < SM; ++sm)
#pragma unroll
    for (int sn = 0; sn < SN; ++sn)
#pragma unroll
      for (int r = 0; r < 4; ++r) {
        const int gm = bm0 + w * WROWS + sm * 16 + kg * 4 + r;
        const int gn = bn0 + sn * 16 + lr;
        outp[(size_t)gm * NDIM + gn] = acc[sm][sn][r];
      }
}

// ---------------- reduce GEMM1 partials (16) + bias + relu -> bf16; also l_out path ----------------
// float4-vectorized: 4 cols/thread, 512 blocks. Same summation order as scalar version.
__global__ __launch_bounds__(256) void fuse_mid(const float* __restrict__ part1,
                                                const float* __restrict__ b1,
                                                const float* __restrict__ lprev,
                                                const float* __restrict__ W2,
                                                const float* __restrict__ b2,
                                                bf16_t* __restrict__ A2)
{
  const int q = blockIdx.x * 256 + threadIdx.x;  // 0..131071
  const int row = q >> 9, c4 = (q & 511) * 4;    // block-uniform branch (c4 chunk of 1024)
  float4 s;
  if (c4 < 1024) {
    s = *(const float4*)(b1 + c4);
#pragma unroll
    for (int i = 0; i < 16; ++i) {
      const float4 p = *(const float4*)(part1 + i * 262144 + row * 1024 + c4);
      s.x += p.x; s.y += p.y; s.z += p.z; s.w += p.w;
    }
  } else {
    const int n = c4 - 1024;
    const float a0 = lprev[2 * row], a1 = lprev[2 * row + 1];
    const float4 w0 = *(const float4*)(W2 + n);
    const float4 w1 = *(const float4*)(W2 + 1024 + n);
    const float4 bb = *(const float4*)(b2 + n);
    s.x = fmaf(a0, w0.x, fmaf(a1, w1.x, bb.x));
    s.y = fmaf(a0, w0.y, fmaf(a1, w1.y, bb.y));
    s.z = fmaf(a0, w0.z, fmaf(a1, w1.z, bb.z));
    s.w = fmaf(a0, w0.w, fmaf(a1, w1.w, bb.w));
  }
  us4 o;
  o[0] = __builtin_bit_cast(unsigned short, (bf16_t)fmaxf(s.x, 0.0f));
  o[1] = __builtin_bit_cast(unsigned short, (bf16_t)fmaxf(s.y, 0.0f));
  o[2] = __builtin_bit_cast(unsigned short, (bf16_t)fmaxf(s.z, 0.0f));
  o[3] = __builtin_bit_cast(unsigned short, (bf16_t)fmaxf(s.w, 0.0f));
  *(us4*)((unsigned short*)A2 + (size_t)row * 2048 + c4) = o;
}

// ---------------- reduce GEMM2 partials (8) + (b3+b4) + relu -> fp32 out (float4) ----------------
__global__ __launch_bounds__(256) void epilogue2(const float* __restrict__ part2,
                                                 const float* __restrict__ b3,
                                                 const float* __restrict__ b4,
                                                 float* __restrict__ out)
{
  const int q = blockIdx.x * 256 + threadIdx.x;  // 0..131071
  const int c4 = (q & 511) * 4;
  const float4 v3 = *(const float4*)(b3 + c4);
  const float4 v4 = *(const float4*)(b4 + c4);
  float4 s = make_float4(v3.x + v4.x, v3.y + v4.y, v3.z + v4.z, v3.w + v4.w);
#pragma unroll
  for (int i = 0; i < 8; ++i) {
    const float4 p = *(const float4*)(part2 + i * 524288 + q * 4);
    s.x += p.x; s.y += p.y; s.z += p.z; s.w += p.w;
  }
  s.x = fmaxf(s.x, 0.0f); s.y = fmaxf(s.y, 0.0f);
  s.z = fmaxf(s.z, 0.0f); s.w = fmaxf(s.w, 0.0f);
  *(float4*)(out + (size_t)q * 4) = s;
}

extern "C" void kernel_launch(void* const* d_in, const int* in_sizes, int n_in,
                              void* d_out, int out_size, void* d_ws, size_t ws_size,
                              hipStream_t stream)
{
  const float* x     = (const float*)d_in[0];
  const float* lprev = (const float*)d_in[1];
  const float* W1    = (const float*)d_in[2];   // (9216, 1024)
  const float* b1    = (const float*)d_in[3];
  const float* W2    = (const float*)d_in[4];   // (2, 1024)
  const float* b2    = (const float*)d_in[5];
  const float* W3    = (const float*)d_in[6];   // (1024, 2048)
  const float* b3    = (const float*)d_in[7];
  const float* W4    = (const float*)d_in[8];   // (1024, 2048)
  const float* b4    = (const float*)d_in[9];
  float* out = (float*)d_out;

  // workspace layout (all 16B aligned), total ~66.6 MB
  char* ws = (char*)d_ws;
  bf16_t* glimpse = (bf16_t*)ws;                 // 256*9216*2    =  4,718,592 B
  bf16_t* A2      = (bf16_t*)(ws + 4718592);     // 256*2048*2    =  1,048,576 B
  float*  part1   = (float*)(ws + 5767168);      // 16*256*1024*4 = 16,777,216 B
  float*  part2   = (float*)(ws + 22544384);     // 8*256*2048*4  = 16,777,216 B
  bf16_t* W1t     = (bf16_t*)(ws + 39321600);    // 1024*9216*2   = 18,874,368 B
  bf16_t* W34t    = (bf16_t*)(ws + 58195968);    // 2048*2048*2   =  8,388,608 B

  // kernel 1: foveation (1792) + W1 transpose (2304) + W34 transpose (1024)
  fov_conv_kernel<<<5120, 256, 0, stream>>>(x, lprev, glimpse, W1, W3, W4, W1t, W34t);
  // kernel 2: GEMM1 M=256,N=1024,K=9216; 128x64 tiles, splitK=16 -> 512 blocks (2/CU)
  gemm_bb<128, 64, 576, 1024, 9216>
      <<<dim3(2, 16, 16), 256, 0, stream>>>(glimpse, W1t, part1);
  // kernel 3: reduce + bias + relu -> A2 (float4, 512 blocks)
  fuse_mid<<<512, 256, 0, stream>>>(part1, b1, lprev, W2, b2, A2);
  // kernel 4: GEMM2 M=256,N=2048,K=2048; 128x64 tiles, splitK=8 -> 512 blocks
  gemm_bb<128, 64, 256, 2048, 2048>
      <<<dim3(2, 32, 8), 256, 0, stream>>>(A2, W34t, part2);
  // kernel 5: reduce + (b3+b4) + relu -> out (float4, 512 blocks)
  epilogue2<<<512, 256, 0, stream>>>(part2, b3, b4, out);
}